// Round 1
// baseline (1902.633 us; speedup 1.0000x reference)
//
#include <hip/hip_runtime.h>
#include <hip/hip_bf16.h>
#include <math.h>

#define N_PTS 65534
#define NTOK (N_PTS*4)
#define GH 180
#define GW 360
#define NCELL (GH*GW)
#define PI_F 3.14159265358979323846f

typedef __bf16 bf16;
typedef bf16 bf16x8 __attribute__((ext_vector_type(8)));
typedef float f32x4 __attribute__((ext_vector_type(4)));

static __device__ __forceinline__ f32x4 mfma16(bf16x8 a, bf16x8 b, f32x4 c){
    return __builtin_amdgcn_mfma_f32_16x16x32_bf16(a, b, c, 0, 0, 0);
}

// ---------------- weight transpose: src K x N (row major) -> dst N x KP bf16, zero-pad k>=K
__global__ void tr_kernel(const float* __restrict__ src, bf16* __restrict__ dst,
                          int K, int N, int KP){
    int idx = blockIdx.x*256 + threadIdx.x;
    if (idx >= N*KP) return;
    int n = idx / KP, k = idx - n*KP;
    float v = (k < K) ? src[(size_t)k*N + n] : 0.f;
    dst[idx] = (bf16)v;
}

// ---------------- per-point grid index + counts
__global__ void count_kernel(const float* __restrict__ x, int* __restrict__ flat,
                             int* __restrict__ cnt){
    int p = blockIdx.x*256 + threadIdx.x;
    if (p >= N_PTS) return;
    float lat = x[p*24+0], lon = x[p*24+1];
    if (lat == -90.0f) lat += 1e-4f;
    int lati = (int)floorf(90.0f - lat);
    int loni = (180 + (int)floorf(lon + 180.0f)) % 360;
    lati = min(max(lati,0),GH-1);
    loni = min(max(loni,0),GW-1);
    int f = lati*GW + loni;
    flat[p] = f;
    atomicAdd(&cnt[f], 1);
}

// ---------------- embed: feat(75, padded to 96) @ W_emb -> h (N_PTS x 512 fp32)
// wave = 32 points (2 M-tiles). block = 4 waves.
__global__ __launch_bounds__(256) void embed_kernel(const float* __restrict__ x,
        const bf16* __restrict__ WT, const float* __restrict__ bemb,
        float* __restrict__ h){
    __shared__ __align__(16) bf16 at[4][32][104];
    const int wv = threadIdx.x >> 6, l = threadIdx.x & 63;
    const int wave = blockIdx.x*4 + wv;
    const int pb = wave*32;
    const int g = l>>4, c = l&15;
    {
        const int pl = l>>1, half = l&1;
        const int p = pb + pl;
        const bool valid = (p < N_PTS);
        float lat=0.f, lon=0.f, t=0.f;
        if (valid){ lat = x[p*24+0]; lon = x[p*24+1]; t = x[p*24+2]; }
        if (lat == -90.0f) lat += 1e-4f;
        float pvs[3];
        pvs[0] = -lat - floorf(-lat);
        pvs[1] =  lon - floorf(lon);
        pvs[2] =  t + 1.0f;
        const int f0 = half ? 38 : 0;
        const int f1 = half ? 96 : 38;
        for (int f = f0; f < f1; ++f){
            float val;
            if (f >= 75) val = 0.f;
            else if (f < 24){
                if (f == 0)      val = lat*(1.f/90.f);
                else if (f == 1) val = lon*(1.f/180.f);
                else if (f == 2) val = t*(1.f/12.f);
                else             val = valid ? x[p*24+f] : 0.f;
            } else if (f < 27) val = pvs[f-24];
            else if (f < 51){ int q=f-27; val = sinf(pvs[q>>3]*(float)(1<<(q&7))*PI_F); }
            else            { int q=f-51; val = cosf(pvs[q>>3]*(float)(1<<(q&7))*PI_F); }
            if (!valid) val = 0.f;
            at[wv][pl][f] = (bf16)val;
        }
    }
    __syncthreads();
    bf16x8 af[2][3];
    for (int mt=0; mt<2; ++mt)
        for (int ks=0; ks<3; ++ks)
            af[mt][ks] = *(const bf16x8*)&at[wv][mt*16+c][ks*32+g*8];
    for (int nt=0; nt<32; ++nt){
        f32x4 a0 = {0.f,0.f,0.f,0.f}, a1 = {0.f,0.f,0.f,0.f};
        const bf16* bp = WT + (size_t)(nt*16+c)*96 + g*8;
        for (int ks=0; ks<3; ++ks){
            bf16x8 b = *(const bf16x8*)(bp + ks*32);
            a0 = mfma16(af[0][ks], b, a0);
            a1 = mfma16(af[1][ks], b, a1);
        }
        float bb = bemb[nt*16+c];
        for (int j=0;j<4;++j){
            int r = g*4+j;
            int p0 = pb + r;
            if (p0 < N_PTS) h[(size_t)p0*512 + nt*16+c] = a0[j] + bb;
            int p1 = pb + 16 + r;
            if (p1 < N_PTS) h[(size_t)p1*512 + nt*16+c] = a1[j] + bb;
        }
    }
}

// ---------------- attention block (one layer): LN1 -> QKV -> attn -> @Wo -> +res
// wave = 8 points = 32 tokens (2 M-tiles of 16). block = 4 independent waves.
__global__ __launch_bounds__(256) void attn_kernel(float* __restrict__ h,
        const bf16* __restrict__ WqkvT, const float* __restrict__ bqkv,
        const bf16* __restrict__ WoT,   const float* __restrict__ bo,
        const float* __restrict__ lns,  const float* __restrict__ lnb){
    __shared__ __align__(16) bf16 at[4][32][136];
    __shared__ __align__(16) bf16 ot[4][32][136];
    const int wv = threadIdx.x>>6, l = threadIdx.x&63;
    const int wave = blockIdx.x*4 + wv;
    const int tb = wave*32;
    const int g = l>>4, c = l&15;
    // --- LN1 into at (bf16). 2 lanes per row, 64 cols each.
    {
        const int r = l>>1, half = l&1;
        const int token = tb + r;
        const float* hp = h + (size_t)token*128 + half*64;
        float s1=0.f, s2=0.f;
        if (token < NTOK){
            for (int i=0;i<16;++i){
                float4 v = ((const float4*)hp)[i];
                s1 += v.x+v.y+v.z+v.w;
                s2 += v.x*v.x+v.y*v.y+v.z*v.z+v.w*v.w;
            }
        }
        s1 += __shfl_xor(s1,1); s2 += __shfl_xor(s2,1);
        float mean = s1*(1.f/128.f);
        float var  = s2*(1.f/128.f) - mean*mean;
        float rs   = rsqrtf(var + 1e-5f);
        if (token < NTOK){
            for (int i=0;i<16;++i){
                float4 v = ((const float4*)hp)[i];
                int cb = half*64 + i*4;
                at[wv][r][cb+0] = (bf16)((v.x-mean)*rs*lns[cb+0]+lnb[cb+0]);
                at[wv][r][cb+1] = (bf16)((v.y-mean)*rs*lns[cb+1]+lnb[cb+1]);
                at[wv][r][cb+2] = (bf16)((v.z-mean)*rs*lns[cb+2]+lnb[cb+2]);
                at[wv][r][cb+3] = (bf16)((v.w-mean)*rs*lns[cb+3]+lnb[cb+3]);
            }
        } else {
            for (int i=0;i<64;++i) at[wv][r][half*64+i] = (bf16)0.f;
        }
    }
    __syncthreads();
    bf16x8 af[2][4];
    for (int mt=0; mt<2; ++mt)
        for (int ks=0; ks<4; ++ks)
            af[mt][ks] = *(const bf16x8*)&at[wv][mt*16+c][ks*32+g*8];
    // --- heads
    for (int hd=0; hd<8; ++hd){
        f32x4 acc[3][2];
        for (int s=0;s<3;++s){
            f32x4 z = {0.f,0.f,0.f,0.f};
            acc[s][0]=z; acc[s][1]=z;
            const bf16* bp = WqkvT + (size_t)(s*128+hd*16+c)*128 + g*8;
            for (int ks=0;ks<4;++ks){
                bf16x8 b = *(const bf16x8*)(bp + ks*32);
                acc[s][0] = mfma16(af[0][ks], b, acc[s][0]);
                acc[s][1] = mfma16(af[1][ks], b, acc[s][1]);
            }
            float bias = bqkv[s*128+hd*16+c];
            for (int mt=0;mt<2;++mt)
                for (int j=0;j<4;++j) acc[s][mt][j] += bias;
        }
        for (int mt=0;mt<2;++mt)
            for (int j=0;j<4;++j) acc[0][mt][j] *= 0.25f; // 1/sqrt(16)
        for (int mt=0; mt<2; ++mt){
            float att[16];
            for (int i=0;i<4;++i)
                for (int j=0;j<4;++j){
                    float t = acc[0][mt][i]*acc[1][mt][j];
                    t += __shfl_xor(t,1); t += __shfl_xor(t,2);
                    t += __shfl_xor(t,4); t += __shfl_xor(t,8);
                    att[i*4+j] = t;
                }
            for (int i=0;i<4;++i){
                float m = fmaxf(fmaxf(att[i*4+0],att[i*4+1]),fmaxf(att[i*4+2],att[i*4+3]));
                float e0=__expf(att[i*4+0]-m), e1=__expf(att[i*4+1]-m);
                float e2=__expf(att[i*4+2]-m), e3=__expf(att[i*4+3]-m);
                float inv = 1.f/(e0+e1+e2+e3);
                float o = (e0*acc[2][mt][0]+e1*acc[2][mt][1]+e2*acc[2][mt][2]+e3*acc[2][mt][3])*inv;
                ot[wv][mt*16+g*4+i][hd*16+c] = (bf16)o;
            }
        }
    }
    __syncthreads();
    // --- o @ Wo + bo + residual
    for (int nt=0; nt<8; ++nt){
        f32x4 a0 = {0.f,0.f,0.f,0.f}, a1 = {0.f,0.f,0.f,0.f};
        const bf16* bp = WoT + (size_t)(nt*16+c)*128 + g*8;
        for (int ks=0;ks<4;++ks){
            bf16x8 b   = *(const bf16x8*)(bp + ks*32);
            bf16x8 oa0 = *(const bf16x8*)&ot[wv][c][ks*32+g*8];
            bf16x8 oa1 = *(const bf16x8*)&ot[wv][16+c][ks*32+g*8];
            a0 = mfma16(oa0, b, a0);
            a1 = mfma16(oa1, b, a1);
        }
        float bb = bo[nt*16+c];
        for (int j=0;j<4;++j){
            int r = g*4+j;
            int t0 = tb + r;
            if (t0 < NTOK){ size_t idx=(size_t)t0*128+nt*16+c; h[idx] += a0[j]+bb; }
            int t1 = tb + 16 + r;
            if (t1 < NTOK){ size_t idx=(size_t)t1*128+nt*16+c; h[idx] += a1[j]+bb; }
        }
    }
}

// ---------------- FFN block (one layer): LN2 -> @Wf1 -> gelu -> @Wf2 -> +res
__global__ __launch_bounds__(256) void ffn_kernel(float* __restrict__ h,
        const bf16* __restrict__ Wf1T, const float* __restrict__ bf1_,
        const bf16* __restrict__ Wf2T, const float* __restrict__ bf2_,
        const float* __restrict__ lns, const float* __restrict__ lnb){
    __shared__ __align__(16) bf16 ft[4][32][136];
    __shared__ __align__(16) bf16 gt[4][32][72];
    const int wv = threadIdx.x>>6, l = threadIdx.x&63;
    const int wave = blockIdx.x*4 + wv;
    const int tb = wave*32;
    const int g = l>>4, c = l&15;
    {
        const int r = l>>1, half = l&1;
        const int token = tb + r;
        const float* hp = h + (size_t)token*128 + half*64;
        float s1=0.f, s2=0.f;
        if (token < NTOK){
            for (int i=0;i<16;++i){
                float4 v = ((const float4*)hp)[i];
                s1 += v.x+v.y+v.z+v.w;
                s2 += v.x*v.x+v.y*v.y+v.z*v.z+v.w*v.w;
            }
        }
        s1 += __shfl_xor(s1,1); s2 += __shfl_xor(s2,1);
        float mean = s1*(1.f/128.f);
        float var  = s2*(1.f/128.f) - mean*mean;
        float rs   = rsqrtf(var + 1e-5f);
        if (token < NTOK){
            for (int i=0;i<16;++i){
                float4 v = ((const float4*)hp)[i];
                int cb = half*64 + i*4;
                ft[wv][r][cb+0] = (bf16)((v.x-mean)*rs*lns[cb+0]+lnb[cb+0]);
                ft[wv][r][cb+1] = (bf16)((v.y-mean)*rs*lns[cb+1]+lnb[cb+1]);
                ft[wv][r][cb+2] = (bf16)((v.z-mean)*rs*lns[cb+2]+lnb[cb+2]);
                ft[wv][r][cb+3] = (bf16)((v.w-mean)*rs*lns[cb+3]+lnb[cb+3]);
            }
        } else {
            for (int i=0;i<64;++i) ft[wv][r][half*64+i] = (bf16)0.f;
        }
    }
    __syncthreads();
    bf16x8 af[2][4];
    for (int mt=0; mt<2; ++mt)
        for (int ks=0; ks<4; ++ks)
            af[mt][ks] = *(const bf16x8*)&ft[wv][mt*16+c][ks*32+g*8];
    f32x4 out[2][8];
    {
        f32x4 z = {0.f,0.f,0.f,0.f};
        for (int mt=0;mt<2;++mt) for (int n=0;n<8;++n) out[mt][n]=z;
    }
    for (int ch=0; ch<8; ++ch){
        // GEMM1 chunk: 64 hidden cols, gelu, to gt (A-layout for GEMM2)
        for (int nt=0; nt<4; ++nt){
            f32x4 a0 = {0.f,0.f,0.f,0.f}, a1 = {0.f,0.f,0.f,0.f};
            const bf16* bp = Wf1T + (size_t)(ch*64+nt*16+c)*128 + g*8;
            for (int ks=0;ks<4;++ks){
                bf16x8 b = *(const bf16x8*)(bp + ks*32);
                a0 = mfma16(af[0][ks], b, a0);
                a1 = mfma16(af[1][ks], b, a1);
            }
            float bb = bf1_[ch*64+nt*16+c];
            for (int mt=0;mt<2;++mt){
                f32x4& a = mt ? a1 : a0;
                for (int j=0;j<4;++j){
                    float xx = a[j] + bb;
                    float zz = 0.7978845608028654f*(xx + 0.044715f*xx*xx*xx);
                    float u  = __expf(2.f*zz);
                    float th = (u-1.f)/(u+1.f);
                    gt[wv][mt*16+g*4+j][nt*16+c] = (bf16)(0.5f*xx*(1.f+th));
                }
            }
        }
        __syncthreads();
        // GEMM2 accumulate over this 64-col k-chunk
        for (int nt2=0; nt2<8; ++nt2){
            const bf16* bp = Wf2T + (size_t)(nt2*16+c)*512 + ch*64 + g*8;
            for (int ks=0;ks<2;++ks){
                bf16x8 b   = *(const bf16x8*)(bp + ks*32);
                bf16x8 ga0 = *(const bf16x8*)&gt[wv][c][ks*32+g*8];
                bf16x8 ga1 = *(const bf16x8*)&gt[wv][16+c][ks*32+g*8];
                out[0][nt2] = mfma16(ga0, b, out[0][nt2]);
                out[1][nt2] = mfma16(ga1, b, out[1][nt2]);
            }
        }
        __syncthreads();
    }
    for (int nt2=0; nt2<8; ++nt2){
        float bb = bf2_[nt2*16+c];
        for (int j=0;j<4;++j){
            int r = g*4+j;
            int t0 = tb + r;
            if (t0 < NTOK){ size_t idx=(size_t)t0*128+nt2*16+c; h[idx] += out[0][nt2][j]+bb; }
            int t1 = tb + 16 + r;
            if (t1 < NTOK){ size_t idx=(size_t)t1*128+nt2*16+c; h[idx] += out[1][nt2][j]+bb; }
        }
    }
}

// ---------------- comb + scatter-mean: y = h(Nx512)@W_comb + b; atomicAdd y/cnt
// wave = 16 points (1 M-tile). block = 4 waves.
__global__ __launch_bounds__(256) void comb_kernel(const float* __restrict__ h,
        const bf16* __restrict__ WT, const float* __restrict__ bcomb,
        const int* __restrict__ flat, const int* __restrict__ cnt,
        float* __restrict__ out){
    __shared__ __align__(16) bf16 at[4][16][520];
    __shared__ int   flS[4][16];
    __shared__ float ivS[4][16];
    const int wv = threadIdx.x>>6, l = threadIdx.x&63;
    const int wave = blockIdx.x*4 + wv;
    const int pb = wave*16;
    const int g = l>>4, c = l&15;
    {
        const int r = l>>2, part = l&3;
        const int p = pb + r;
        const float* hp = h + (size_t)p*512 + part*128;
        if (p < N_PTS){
            for (int i=0;i<32;++i){
                float4 v = ((const float4*)hp)[i];
                int cb = part*128 + i*4;
                at[wv][r][cb+0]=(bf16)v.x; at[wv][r][cb+1]=(bf16)v.y;
                at[wv][r][cb+2]=(bf16)v.z; at[wv][r][cb+3]=(bf16)v.w;
            }
        } else {
            for (int i=0;i<128;++i) at[wv][r][part*128+i]=(bf16)0.f;
        }
    }
    if (l < 16){
        int p = pb + l; int fl = 0; float iv = 0.f;
        if (p < N_PTS){ fl = flat[p]; float cv = (float)cnt[fl]; iv = 1.f/fmaxf(cv,1.f); }
        flS[wv][l] = fl; ivS[wv][l] = iv;
    }
    __syncthreads();
    bf16x8 af[16];
    for (int ks=0; ks<16; ++ks)
        af[ks] = *(const bf16x8*)&at[wv][c][ks*32+g*8];
    for (int nt=0; nt<32; ++nt){
        f32x4 acc = {0.f,0.f,0.f,0.f};
        const bf16* bp = WT + (size_t)(nt*16+c)*512 + g*8;
        for (int ks=0; ks<16; ++ks){
            bf16x8 b = *(const bf16x8*)(bp + ks*32);
            acc = mfma16(af[ks], b, acc);
        }
        float bb = bcomb[nt*16+c];
        for (int j=0;j<4;++j){
            int r = g*4+j;
            int p = pb + r;
            if (p < N_PTS){
                float val = (acc[j] + bb) * ivS[wv][r];
                atomicAdd(&out[(size_t)flS[wv][r]*512 + nt*16 + c], val);
            }
        }
    }
}

extern "C" void kernel_launch(void* const* d_in, const int* in_sizes, int n_in,
                              void* d_out, int out_size, void* d_ws, size_t ws_size,
                              hipStream_t stream){
    (void)in_sizes; (void)n_in; (void)ws_size;
    const float* x      = (const float*)d_in[0];
    const float* W_emb  = (const float*)d_in[1];
    const float* b_emb  = (const float*)d_in[2];
    const float* ln1_s  = (const float*)d_in[3];
    const float* ln1_b  = (const float*)d_in[4];
    const float* Wqkv   = (const float*)d_in[5];
    const float* bqkv   = (const float*)d_in[6];
    const float* Wo     = (const float*)d_in[7];
    const float* bo     = (const float*)d_in[8];
    const float* ln2_s  = (const float*)d_in[9];
    const float* ln2_b  = (const float*)d_in[10];
    const float* Wf1    = (const float*)d_in[11];
    const float* bf1    = (const float*)d_in[12];
    const float* Wf2    = (const float*)d_in[13];
    const float* bf2    = (const float*)d_in[14];
    const float* W_comb = (const float*)d_in[15];
    const float* b_comb = (const float*)d_in[16];
    float* out = (float*)d_out;

    char* ws = (char*)d_ws;
    size_t off = 0;
    auto alloc = [&](size_t bytes)->char*{
        char* p = ws + off; off = (off + bytes + 255) & ~(size_t)255; return p;
    };
    float* h     = (float*)alloc((size_t)N_PTS*512*4);
    int*   flat  = (int*)  alloc((size_t)N_PTS*4);
    int*   cnt   = (int*)  alloc((size_t)NCELL*4);
    bf16*  WembT = (bf16*) alloc((size_t)512*96*2);
    bf16*  WqkvT = (bf16*) alloc((size_t)2*384*128*2);
    bf16*  WoT   = (bf16*) alloc((size_t)2*128*128*2);
    bf16*  Wf1T  = (bf16*) alloc((size_t)2*512*128*2);
    bf16*  Wf2T  = (bf16*) alloc((size_t)2*128*512*2);
    bf16*  WcT   = (bf16*) alloc((size_t)512*512*2);

    hipMemsetAsync(d_out, 0, (size_t)out_size*sizeof(float), stream);
    hipMemsetAsync(cnt, 0, (size_t)NCELL*4, stream);

    auto tr = [&](const float* s, bf16* d, int K, int N, int KP){
        int tot = N*KP;
        tr_kernel<<<(tot+255)/256, 256, 0, stream>>>(s, d, K, N, KP);
    };
    tr(W_emb, WembT, 75, 512, 96);
    for (int ly=0; ly<2; ++ly){
        tr(Wqkv + (size_t)ly*128*384, WqkvT + (size_t)ly*384*128, 128, 384, 128);
        tr(Wo   + (size_t)ly*128*128, WoT   + (size_t)ly*128*128, 128, 128, 128);
        tr(Wf1  + (size_t)ly*128*512, Wf1T  + (size_t)ly*512*128, 128, 512, 128);
        tr(Wf2  + (size_t)ly*512*128, Wf2T  + (size_t)ly*128*512, 512, 128, 512);
    }
    tr(W_comb, WcT, 512, 512, 512);

    count_kernel<<<(N_PTS+255)/256, 256, 0, stream>>>(x, flat, cnt);
    embed_kernel<<<512, 256, 0, stream>>>(x, WembT, b_emb, h);
    for (int ly=0; ly<2; ++ly){
        attn_kernel<<<2048, 256, 0, stream>>>(h,
            WqkvT + (size_t)ly*384*128, bqkv + ly*384,
            WoT   + (size_t)ly*128*128, bo   + ly*128,
            ln1_s + ly*128, ln1_b + ly*128);
        ffn_kernel<<<2048, 256, 0, stream>>>(h,
            Wf1T + (size_t)ly*512*128, bf1 + ly*512,
            Wf2T + (size_t)ly*128*512, bf2 + ly*128,
            ln2_s + ly*128, ln2_b + ly*128);
    }
    comb_kernel<<<1024, 256, 0, stream>>>(h, WcT, b_comb, flat, cnt, out);
}

// Round 2
// 1032.943 us; speedup vs baseline: 1.8420x; 1.8420x over previous
//
#include <hip/hip_runtime.h>
#include <hip/hip_bf16.h>
#include <math.h>

#define N_PTS 65534
#define GH 180
#define GW 360
#define NCELL (GH*GW)
#define PI_F 3.14159265358979323846f

typedef __bf16 bf16;
typedef bf16 bf16x8 __attribute__((ext_vector_type(8)));
typedef float f32x4 __attribute__((ext_vector_type(4)));

static __device__ __forceinline__ f32x4 mfma16(bf16x8 a, bf16x8 b, f32x4 c){
    return __builtin_amdgcn_mfma_f32_16x16x32_bf16(a,b,c,0,0,0);
}

// ---------------- generic transpose: src K x N (row major) -> dst N x KP bf16, zero-pad k>=K
__global__ void tr_kernel(const float* __restrict__ src, bf16* __restrict__ dst,
                          int K, int N, int KP){
    int idx = blockIdx.x*256 + threadIdx.x;
    if (idx >= N*KP) return;
    int n = idx / KP, k = idx - n*KP;
    float v = (k < K) ? src[(size_t)k*N + n] : 0.f;
    dst[idx] = (bf16)v;
}

// Wqkv (2,128,384) -> WqT [lay][hd][s][d=16][k=128]
__global__ void tr_qkv_kernel(const float* __restrict__ src, bf16* __restrict__ dst){
    int idx = blockIdx.x*256 + threadIdx.x;
    if (idx >= 2*49152) return;
    int lay = idx / 49152, r = idx % 49152;
    int hd = r / 6144,  r2 = r % 6144;
    int s3 = r2 / 2048, r3 = r2 % 2048;
    int d  = r3 / 128,  k  = r3 % 128;
    dst[idx] = (bf16)src[(size_t)lay*49152 + (size_t)k*384 + s3*128 + hd*16 + d];
}

// Wf2 (2,512,128) -> Wf2C [lay][ch=8][n=128][kk=64]
__global__ void tr_f2_kernel(const float* __restrict__ src, bf16* __restrict__ dst){
    int idx = blockIdx.x*256 + threadIdx.x;
    if (idx >= 2*65536) return;
    int lay = idx / 65536, r = idx % 65536;
    int ch = r / 8192, r2 = r % 8192;
    int n  = r2 / 64,  kk = r2 % 64;
    dst[idx] = (bf16)src[(size_t)lay*65536 + (size_t)(ch*64+kk)*128 + n];
}

// ---------------- per-point grid index + counts
__global__ void count_kernel(const float* __restrict__ x, int* __restrict__ flat,
                             int* __restrict__ cnt){
    int p = blockIdx.x*256 + threadIdx.x;
    if (p >= N_PTS) return;
    float lat = x[p*24+0], lon = x[p*24+1];
    if (lat == -90.0f) lat += 1e-4f;
    int lati = (int)floorf(90.0f - lat);
    int loni = (180 + (int)floorf(lon + 180.0f)) % 360;
    lati = min(max(lati,0),GH-1);
    loni = min(max(loni,0),GW-1);
    int f = lati*GW + loni;
    flat[p] = f;
    atomicAdd(&cnt[f], 1);
}

// stage a [rows x rowElems] bf16 block from global into wbuf with padded row stride
__device__ __forceinline__ void stage_pad(const bf16* __restrict__ g, bf16* wbuf,
                                          int rows, int rowElems, int ldsStride, int tid){
    const int rowBytes = rowElems*2;
    const int total = rows*rowBytes;
    for (int off = tid*16; off < total; off += 4096){
        int r = off / rowBytes, k = off - r*rowBytes;
        *(int4*)((char*)wbuf + r*ldsStride*2 + k) = *(const int4*)((const char*)g + off);
    }
}

#define STAGE(src, rows, rowElems, ldsStride) do { \
    __syncthreads(); \
    stage_pad((src), wbuf, (rows), (rowElems), (ldsStride), tid); \
    __syncthreads(); } while(0)

// ================= fully fused: features -> embed -> 2 transformer layers -> comb -> scatter
// wave = 8 points = 32 tokens (2 M-tiles). block = 4 waves. h stays in registers.
__global__ __launch_bounds__(256,3) void fused_kernel(
    const float* __restrict__ x,
    const bf16* __restrict__ WembT, const float* __restrict__ b_emb,
    const bf16* __restrict__ WqT,   const float* __restrict__ bqkv,
    const bf16* __restrict__ WoT,   const float* __restrict__ bo,
    const bf16* __restrict__ Wf1T,  const float* __restrict__ bf1,
    const bf16* __restrict__ Wf2C,  const float* __restrict__ bf2,
    const bf16* __restrict__ WcT,   const float* __restrict__ b_comb,
    const float* __restrict__ ln1s, const float* __restrict__ ln1b,
    const float* __restrict__ ln2s, const float* __restrict__ ln2b,
    const int* __restrict__ flat,   const int* __restrict__ cnt,
    float* __restrict__ out)
{
    __shared__ __align__(16) bf16 tile[4][32][136];   // per-wave A/ot/gt tile (34,816 B)
    __shared__ __align__(16) bf16 wbuf[9216];         // shared weight chunk (18,432 B)
    const int tid = threadIdx.x;
    const int wv = tid>>6, l = tid&63;
    const int g = l>>4, c = l&15;
    const int pb = blockIdx.x*32 + wv*8;

    // ---- features into tile rows 0..7 (points), rows 8..15 zeroed (M-tile pad)
    {
        const int pl = l>>3, w = l&7;
        const int p = pb + pl;
        const bool valid = (p < N_PTS);
        float lat=0.f, lon=0.f, t=0.f;
        if (valid){ lat=x[p*24+0]; lon=x[p*24+1]; t=x[p*24+2]; }
        if (lat == -90.0f) lat += 1e-4f;
        float pvs[3] = { -lat - floorf(-lat), lon - floorf(lon), t + 1.0f };
        #pragma unroll
        for (int i=0;i<12;++i){
            int f = w*12 + i;
            float val;
            if (f >= 75) val = 0.f;
            else if (f < 24){
                if (f==0)      val = lat*(1.f/90.f);
                else if (f==1) val = lon*(1.f/180.f);
                else if (f==2) val = t*(1.f/12.f);
                else           val = valid ? x[p*24+f] : 0.f;
            } else if (f<27) val = pvs[f-24];
            else if (f<51){ int q=f-27; val = sinf(pvs[q>>3]*(float)(1<<(q&7))*PI_F); }
            else          { int q=f-51; val = cosf(pvs[q>>3]*(float)(1<<(q&7))*PI_F); }
            if (!valid) val = 0.f;
            tile[wv][pl][f]   = (bf16)val;
            tile[wv][8+pl][f] = (bf16)0.f;
        }
    }
    // embed A-frags (rows = points 0..15, K=96)
    bf16x8 afe[3];
    #pragma unroll
    for (int ks=0;ks<3;++ks) afe[ks] = *(const bf16x8*)&tile[wv][c][ks*32+g*8];

    f32x4 h[2][8];
    float* tf = (float*)&tile[wv][0][0];   // 8x64 f32 bounce (2 KB), tile is free after afe load
    // ---- embed: 8 chunks of 64 output cols
    for (int ch=0; ch<8; ++ch){
        STAGE(WembT + ch*64*96, 64, 96, 104);
        const int tk = ch>>1;
        #pragma unroll
        for (int nt=0; nt<4; ++nt){
            f32x4 acc = {0.f,0.f,0.f,0.f};
            const bf16* bp = wbuf + (nt*16+c)*104 + g*8;
            #pragma unroll
            for (int ks=0;ks<3;++ks)
                acc = mfma16(afe[ks], *(const bf16x8*)(bp+ks*32), acc);
            float bb = b_emb[ch*64 + nt*16 + c];
            if (g<2){
                #pragma unroll
                for (int j=0;j<4;++j) tf[(g*4+j)*64 + nt*16 + c] = acc[j] + bb;
            }
        }
        #pragma unroll
        for (int mt=0;mt<2;++mt)
            #pragma unroll
            for (int nt=0;nt<4;++nt)
                h[mt][(ch&1)*4+nt][tk] = tf[(mt*4+g)*64 + nt*16 + c];
    }
    __syncthreads();   // fence float-typed tf reads vs upcoming bf16 tile writes

    // ---- transformer layers
    for (int lay=0; lay<2; ++lay){
        float ls[8], lb[8];
        // ===== LN1 -> tile (bf16)
        #pragma unroll
        for (int n=0;n<8;++n){ ls[n]=ln1s[lay*128+n*16+c]; lb[n]=ln1b[lay*128+n*16+c]; }
        #pragma unroll
        for (int mt=0;mt<2;++mt)
            #pragma unroll
            for (int j=0;j<4;++j){
                float s=0.f,q=0.f;
                #pragma unroll
                for (int n=0;n<8;++n){ float v=h[mt][n][j]; s+=v; q+=v*v; }
                s += __shfl_xor(s,1); s += __shfl_xor(s,2); s += __shfl_xor(s,4); s += __shfl_xor(s,8);
                q += __shfl_xor(q,1); q += __shfl_xor(q,2); q += __shfl_xor(q,4); q += __shfl_xor(q,8);
                float m = s*(1.f/128.f);
                float var = q*(1.f/128.f) - m*m;
                float rs = rsqrtf(var + 1e-5f);
                #pragma unroll
                for (int n=0;n<8;++n)
                    tile[wv][mt*16+g*4+j][n*16+c] = (bf16)((h[mt][n][j]-m)*rs*ls[n]+lb[n]);
            }
        bf16x8 af[2][4];
        #pragma unroll
        for (int mt=0;mt<2;++mt)
            #pragma unroll
            for (int ks=0;ks<4;++ks)
                af[mt][ks] = *(const bf16x8*)&tile[wv][mt*16+c][ks*32+g*8];
        // ===== QKV + in-register attention, per head (ot overwrites tile)
        for (int hd=0; hd<8; ++hd){
            STAGE(WqT + (lay*8+hd)*6144, 48, 128, 136);
            f32x4 acc[3][2];
            #pragma unroll
            for (int s3=0;s3<3;++s3){
                float bias = bqkv[lay*384 + s3*128 + hd*16 + c];
                #pragma unroll
                for (int mt=0;mt<2;++mt){
                    f32x4 a = {0.f,0.f,0.f,0.f};
                    const bf16* bp = wbuf + (s3*16+c)*136 + g*8;
                    #pragma unroll
                    for (int ks=0;ks<4;++ks)
                        a = mfma16(af[mt][ks], *(const bf16x8*)(bp+ks*32), a);
                    #pragma unroll
                    for (int j=0;j<4;++j) a[j] += bias;
                    acc[s3][mt] = a;
                }
            }
            #pragma unroll
            for (int mt=0;mt<2;++mt){
                #pragma unroll
                for (int j=0;j<4;++j) acc[0][mt][j] *= 0.25f;
                float att[16];
                #pragma unroll
                for (int i=0;i<4;++i)
                    #pragma unroll
                    for (int j=0;j<4;++j){
                        float t = acc[0][mt][i]*acc[1][mt][j];
                        t += __shfl_xor(t,1); t += __shfl_xor(t,2);
                        t += __shfl_xor(t,4); t += __shfl_xor(t,8);
                        att[i*4+j]=t;
                    }
                #pragma unroll
                for (int i=0;i<4;++i){
                    float m = fmaxf(fmaxf(att[i*4],att[i*4+1]),fmaxf(att[i*4+2],att[i*4+3]));
                    float e0=__expf(att[i*4]-m),   e1=__expf(att[i*4+1]-m);
                    float e2=__expf(att[i*4+2]-m), e3=__expf(att[i*4+3]-m);
                    float inv = 1.f/(e0+e1+e2+e3);
                    float o = (e0*acc[2][mt][0]+e1*acc[2][mt][1]+e2*acc[2][mt][2]+e3*acc[2][mt][3])*inv;
                    tile[wv][mt*16+g*4+i][hd*16+c] = (bf16)o;
                }
            }
        }
        // ===== O-proj, residual accumulates in h
        bf16x8 oa[2][4];
        #pragma unroll
        for (int mt=0;mt<2;++mt)
            #pragma unroll
            for (int ks=0;ks<4;++ks)
                oa[mt][ks] = *(const bf16x8*)&tile[wv][mt*16+c][ks*32+g*8];
        for (int chk=0; chk<2; ++chk){
            STAGE(WoT + lay*16384 + chk*64*128, 64, 128, 136);
            #pragma unroll
            for (int nt=0;nt<4;++nt){
                int nh = chk*4+nt;
                float bias = bo[lay*128 + nh*16 + c];
                #pragma unroll
                for (int mt=0;mt<2;++mt){
                    f32x4 a = h[mt][nh];
                    const bf16* bp = wbuf + (nt*16+c)*136 + g*8;
                    #pragma unroll
                    for (int ks=0;ks<4;++ks)
                        a = mfma16(oa[mt][ks], *(const bf16x8*)(bp+ks*32), a);
                    #pragma unroll
                    for (int j=0;j<4;++j) a[j]+=bias;
                    h[mt][nh]=a;
                }
            }
        }
        // ===== LN2 -> tile
        #pragma unroll
        for (int n=0;n<8;++n){ ls[n]=ln2s[lay*128+n*16+c]; lb[n]=ln2b[lay*128+n*16+c]; }
        #pragma unroll
        for (int mt=0;mt<2;++mt)
            #pragma unroll
            for (int j=0;j<4;++j){
                float s=0.f,q=0.f;
                #pragma unroll
                for (int n=0;n<8;++n){ float v=h[mt][n][j]; s+=v; q+=v*v; }
                s += __shfl_xor(s,1); s += __shfl_xor(s,2); s += __shfl_xor(s,4); s += __shfl_xor(s,8);
                q += __shfl_xor(q,1); q += __shfl_xor(q,2); q += __shfl_xor(q,4); q += __shfl_xor(q,8);
                float m = s*(1.f/128.f);
                float var = q*(1.f/128.f) - m*m;
                float rs = rsqrtf(var + 1e-5f);
                #pragma unroll
                for (int n=0;n<8;++n)
                    tile[wv][mt*16+g*4+j][n*16+c] = (bf16)((h[mt][n][j]-m)*rs*ls[n]+lb[n]);
            }
        bf16x8 f1a[2][4];
        #pragma unroll
        for (int mt=0;mt<2;++mt)
            #pragma unroll
            for (int ks=0;ks<4;++ks)
                f1a[mt][ks] = *(const bf16x8*)&tile[wv][mt*16+c][ks*32+g*8];
        // ===== FFN: 8 chunks of 64 hidden cols; FFN2 accumulates into h (residual)
        for (int ch=0; ch<8; ++ch){
            STAGE(Wf1T + lay*65536 + ch*64*128, 64, 128, 136);
            #pragma unroll
            for (int nt=0;nt<4;++nt){
                float bias = bf1[lay*512 + ch*64 + nt*16 + c];
                #pragma unroll
                for (int mt=0;mt<2;++mt){
                    f32x4 a = {0.f,0.f,0.f,0.f};
                    const bf16* bp = wbuf + (nt*16+c)*136 + g*8;
                    #pragma unroll
                    for (int ks=0;ks<4;++ks)
                        a = mfma16(f1a[mt][ks], *(const bf16x8*)(bp+ks*32), a);
                    #pragma unroll
                    for (int j=0;j<4;++j){
                        float xx = a[j]+bias;
                        float zz = 0.7978845608028654f*(xx+0.044715f*xx*xx*xx);
                        float u  = __expf(2.f*zz);
                        float th = (u-1.f)/(u+1.f);
                        tile[wv][mt*16+g*4+j][nt*16+c] = (bf16)(0.5f*xx*(1.f+th));
                    }
                }
            }
            STAGE(Wf2C + (lay*8+ch)*8192, 128, 64, 72);
            bf16x8 ga[2][2];
            #pragma unroll
            for (int mt=0;mt<2;++mt)
                #pragma unroll
                for (int ks=0;ks<2;++ks)
                    ga[mt][ks] = *(const bf16x8*)&tile[wv][mt*16+c][ks*32+g*8];
            #pragma unroll
            for (int nt2=0;nt2<8;++nt2){
                const bf16* bp = wbuf + (nt2*16+c)*72 + g*8;
                #pragma unroll
                for (int mt=0;mt<2;++mt){
                    f32x4 a = h[mt][nt2];
                    #pragma unroll
                    for (int ks=0;ks<2;++ks)
                        a = mfma16(ga[mt][ks], *(const bf16x8*)(bp+ks*32), a);
                    h[mt][nt2]=a;
                }
            }
        }
        #pragma unroll
        for (int nt2=0;nt2<8;++nt2){
            float bias = bf2[lay*128 + nt2*16+c];
            #pragma unroll
            for (int mt=0;mt<2;++mt)
                #pragma unroll
                for (int j=0;j<4;++j) h[mt][nt2][j]+=bias;
        }
    }

    // ---- comb + scatter-mean. tk-split GEMMs reuse the token-major tile.
    #pragma unroll
    for (int mt=0;mt<2;++mt)
        #pragma unroll
        for (int n=0;n<8;++n)
            #pragma unroll
            for (int j=0;j<4;++j)
                tile[wv][mt*16+g*4+j][n*16+c] = (bf16)h[mt][n][j];
    bf16x8 afc[4][4];
    #pragma unroll
    for (int tk=0;tk<4;++tk)
        #pragma unroll
        for (int ks=0;ks<4;++ks)
            afc[tk][ks] = *(const bf16x8*)&tile[wv][(c&7)*4+tk][ks*32+g*8];
    int flj[4]; float ivj[4];
    #pragma unroll
    for (int j=0;j<4;++j){
        int p = pb + g*4 + j;
        if (g<2 && p<N_PTS){ int f=flat[p]; flj[j]=f; ivj[j]=1.f/fmaxf((float)cnt[f],1.f); }
        else { flj[j]=0; ivj[j]=0.f; }
    }
    for (int chk=0; chk<32; ++chk){
        STAGE(WcT + chk*8192, 16, 512, 520);
        f32x4 a = {0.f,0.f,0.f,0.f};
        const bf16* bp = wbuf + c*520 + g*8;
        #pragma unroll
        for (int tk=0;tk<4;++tk)
            #pragma unroll
            for (int ks=0;ks<4;++ks)
                a = mfma16(afc[tk][ks], *(const bf16x8*)(bp + tk*128 + ks*32), a);
        if (g<2){
            float bb = b_comb[chk*16+c];
            #pragma unroll
            for (int j=0;j<4;++j){
                int p = pb + g*4 + j;
                if (p < N_PTS)
                    atomicAdd(&out[(size_t)flj[j]*512 + chk*16 + c], (a[j]+bb)*ivj[j]);
            }
        }
    }
}

extern "C" void kernel_launch(void* const* d_in, const int* in_sizes, int n_in,
                              void* d_out, int out_size, void* d_ws, size_t ws_size,
                              hipStream_t stream){
    (void)in_sizes; (void)n_in; (void)ws_size;
    const float* x      = (const float*)d_in[0];
    const float* W_emb  = (const float*)d_in[1];
    const float* b_emb  = (const float*)d_in[2];
    const float* ln1_s  = (const float*)d_in[3];
    const float* ln1_b  = (const float*)d_in[4];
    const float* Wqkv   = (const float*)d_in[5];
    const float* bqkv   = (const float*)d_in[6];
    const float* Wo     = (const float*)d_in[7];
    const float* bo     = (const float*)d_in[8];
    const float* ln2_s  = (const float*)d_in[9];
    const float* ln2_b  = (const float*)d_in[10];
    const float* Wf1    = (const float*)d_in[11];
    const float* bf1    = (const float*)d_in[12];
    const float* Wf2    = (const float*)d_in[13];
    const float* bf2    = (const float*)d_in[14];
    const float* W_comb = (const float*)d_in[15];
    const float* b_comb = (const float*)d_in[16];
    float* out = (float*)d_out;

    char* ws = (char*)d_ws;
    size_t off = 0;
    auto alloc = [&](size_t bytes)->char*{
        char* p = ws + off; off = (off + bytes + 255) & ~(size_t)255; return p;
    };
    bf16* WembT = (bf16*) alloc((size_t)512*96*2);
    bf16* WqT   = (bf16*) alloc((size_t)2*49152*2);
    bf16* WoT   = (bf16*) alloc((size_t)2*16384*2);
    bf16* Wf1T  = (bf16*) alloc((size_t)2*65536*2);
    bf16* Wf2C  = (bf16*) alloc((size_t)2*65536*2);
    bf16* WcT   = (bf16*) alloc((size_t)512*512*2);
    int*  flat  = (int*)  alloc((size_t)N_PTS*4);
    int*  cnt   = (int*)  alloc((size_t)NCELL*4);

    hipMemsetAsync(d_out, 0, (size_t)out_size*sizeof(float), stream);
    hipMemsetAsync(cnt, 0, (size_t)NCELL*4, stream);

    auto tr = [&](const float* s, bf16* d, int K, int N, int KP){
        int tot = N*KP;
        tr_kernel<<<(tot+255)/256, 256, 0, stream>>>(s, d, K, N, KP);
    };
    tr(W_emb, WembT, 75, 512, 96);
    tr_qkv_kernel<<<(2*49152+255)/256, 256, 0, stream>>>(Wqkv, WqT);
    for (int lay=0; lay<2; ++lay){
        tr(Wo  + (size_t)lay*16384, WoT  + (size_t)lay*16384, 128, 128, 128);
        tr(Wf1 + (size_t)lay*65536, Wf1T + (size_t)lay*65536, 128, 512, 128);
    }
    tr_f2_kernel<<<(2*65536+255)/256, 256, 0, stream>>>(Wf2, Wf2C);
    tr(W_comb, WcT, 512, 512, 512);

    count_kernel<<<(N_PTS+255)/256, 256, 0, stream>>>(x, flat, cnt);

    fused_kernel<<<2048, 256, 0, stream>>>(x,
        WembT, b_emb, WqT, bqkv, WoT, bo, Wf1T, bf1, Wf2C, bf2, WcT, b_comb,
        ln1_s, ln1_b, ln2_s, ln2_b, flat, cnt, out);
}